// Round 4
// baseline (180.223 us; speedup 1.0000x reference)
//
#include <hip/hip_runtime.h>
#include <math.h>

#define B 16
#define C 512
#define L 8192
#define PP 128
#define TILE_L 32
#define TPB 8                       // tiles per block sweep
#define NB (L / (TILE_L * TPB))     // 32 partial-blocks per batch
#define LN_EPS 1e-5f

typedef float fx4 __attribute__((ext_vector_type(4)));

// ---- Fused: scores + running flash softmax + partial context. ----
// Grid (NB, B), 512 threads. Tile = 32 l x 512 c (64 KB, L2-resident for phase 2).
// Phase 1: thread (rg=tid>>5, l_ofs=tid&31) -> coalesced scalar loads, LDS reduce.
// Phase 2: thread c=tid sweeps its row's 32 l as float4 (L2 hits), 1 accumulator.
__global__ __launch_bounds__(512) void k_fused(
    const float* __restrict__ x, const float* __restrict__ cw,
    float* __restrict__ part_pc, float* __restrict__ part_m, float* __restrict__ part_z) {
  const int b = blockIdx.y;
  const int blk = blockIdx.x;
  const int tid = threadIdx.x;
  const int l_ofs = tid & 31;
  const int rg = tid >> 5;           // 0..15

  __shared__ float scw[C];
  __shared__ float sred[16][32];
  __shared__ float pw[TILE_L];
  __shared__ float s_m, s_z, s_resc;

  scw[tid] = cw[tid];
  if (tid == 0) { s_m = -INFINITY; s_z = 0.f; }

  float pc_acc = 0.f;
  const size_t xbase = (size_t)b * C * L;

  for (int t = 0; t < TPB; ++t) {
    const int l0 = (blk * TPB + t) * TILE_L;
    __syncthreads();                 // sred/pw reuse-safe; scw/s_m visible at t=0

    // Phase 1: partial scores, coalesced over l.
    float ps = 0.f;
    const float* xp = x + xbase + l0 + l_ofs;
    #pragma unroll
    for (int i = 0; i < 32; ++i) {
      const int c = (rg << 5) + i;
      ps += xp[(size_t)c * L] * scw[c];
    }
    sred[rg][l_ofs] = ps;
    __syncthreads();

    // Wave 0 (lanes 0..31): finalize 32 scores, online softmax update.
    if (tid < 32) {
      float s = 0.f;
      #pragma unroll
      for (int g = 0; g < 16; ++g) s += sred[g][tid];
      float m = s;
      #pragma unroll
      for (int off = 16; off; off >>= 1) m = fmaxf(m, __shfl_xor(m, off, 32));
      const float mold = s_m;
      const float mnew = fmaxf(mold, m);
      const float p = __expf(s - mnew);
      float z = p;
      #pragma unroll
      for (int off = 16; off; off >>= 1) z += __shfl_xor(z, off, 32);
      pw[tid] = p;
      if (tid == 0) {
        const float resc = __expf(mold - mnew);   // t=0: exp(-inf)=0, zeroes acc
        s_resc = resc;
        s_z = s_z * resc + z;
        s_m = mnew;
      }
    }
    __syncthreads();

    // Phase 2: thread-per-channel, float4 row sweep (L2-resident), 1 accumulator.
    const fx4* xr4 = (const fx4*)(x + xbase + (size_t)tid * L + l0);
    float pv = 0.f;
    #pragma unroll
    for (int j = 0; j < 8; ++j) {
      const fx4 v = xr4[j];
      pv += v.x * pw[4 * j] + v.y * pw[4 * j + 1] + v.z * pw[4 * j + 2] + v.w * pw[4 * j + 3];
    }
    pc_acc = pc_acc * s_resc + pv;
  }

  part_pc[(size_t)(b * NB + blk) * C + tid] = pc_acc;   // coalesced
  if (tid == 0) {
    part_m[b * NB + blk] = s_m;
    part_z[b * NB + blk] = s_z;
  }
}

// ---- Tail: flash-combine 32 partials -> context -> MLP(LN,ReLU) -> add_term ----
__global__ void k_tail(const float* __restrict__ part_pc, const float* __restrict__ part_m,
                       const float* __restrict__ part_z,
                       const float* __restrict__ w1, const float* __restrict__ b1,
                       const float* __restrict__ lnw, const float* __restrict__ lnb,
                       const float* __restrict__ w2, const float* __restrict__ b2,
                       float* __restrict__ add_term) {
  const int b = blockIdx.x;
  const int tid = threadIdx.x;   // 512 threads
  __shared__ float se[NB];
  __shared__ float sctx[C];
  __shared__ float st[PP];

  if (tid < 64) {
    const float m = (tid < NB) ? part_m[b * NB + tid] : -INFINITY;
    float M = m;
    #pragma unroll
    for (int off = 16; off; off >>= 1) M = fmaxf(M, __shfl_xor(M, off, 32));
    const float e = (tid < NB) ? __expf(m - M) : 0.f;
    float Z = (tid < NB) ? part_z[b * NB + tid] * e : 0.f;
    #pragma unroll
    for (int off = 16; off; off >>= 1) Z += __shfl_xor(Z, off, 32);
    if (tid < NB) se[tid] = e / Z;
  }
  __syncthreads();

  // context[b, tid]
  float acc = 0.f;
  const float* pp = part_pc + (size_t)b * NB * C + tid;
  #pragma unroll
  for (int t = 0; t < NB; ++t) acc += pp[(size_t)t * C] * se[t];
  sctx[tid] = acc;
  __syncthreads();

  // t = w1 @ ctx + b1 (4 threads per output p)
  {
    const int p = tid >> 2;
    const int q = tid & 3;
    const float* w1r = w1 + (size_t)p * C + q * 128;
    const float* cx = &sctx[q * 128];
    float a = 0.f;
    #pragma unroll 8
    for (int cc = 0; cc < 128; ++cc) a += w1r[cc] * cx[cc];
    a += __shfl_xor(a, 1);
    a += __shfl_xor(a, 2);
    if (q == 0) st[p] = a + b1[p];
  }
  __syncthreads();

  // LayerNorm over P + ReLU
  float tv = 0.f;
  if (tid < PP) {
    float mu = 0.f;
    #pragma unroll 8
    for (int pi = 0; pi < PP; ++pi) mu += st[pi];
    mu *= (1.f / PP);
    float var = 0.f;
    #pragma unroll 8
    for (int pi = 0; pi < PP; ++pi) { const float d = st[pi] - mu; var += d * d; }
    var *= (1.f / PP);
    tv = (st[tid] - mu) * rsqrtf(var + LN_EPS) * lnw[tid] + lnb[tid];
    tv = fmaxf(tv, 0.f);
  }
  __syncthreads();
  if (tid < PP) st[tid] = tv;
  __syncthreads();

  // add_term[c] = w2[c,:] @ t + b2[c]
  float a2 = b2[tid];
  const float* w2r = w2 + (size_t)tid * PP;
  #pragma unroll 8
  for (int pi = 0; pi < PP; ++pi) a2 += w2r[pi] * st[pi];
  add_term[b * C + tid] = a2;
}

// ---- out[b,c,:] = x[b,c,:] + add_term[b,c]; NT stores keep x resident in L3 ----
__global__ void k_add(const float* __restrict__ x, const float* __restrict__ at,
                      float* __restrict__ out) {
  const int bc = blockIdx.x;
  const float a = at[bc];
  const fx4* xr = (const fx4*)(x + (size_t)bc * L);
  fx4* orow = (fx4*)(out + (size_t)bc * L);
  #pragma unroll 4
  for (int i = threadIdx.x; i < L / 4; i += 256) {
    fx4 v = xr[i];
    v = v + a;
    __builtin_nontemporal_store(v, &orow[i]);
  }
}

extern "C" void kernel_launch(void* const* d_in, const int* in_sizes, int n_in,
                              void* d_out, int out_size, void* d_ws, size_t ws_size,
                              hipStream_t stream) {
  const float* x   = (const float*)d_in[0];
  const float* cw  = (const float*)d_in[1];
  // d_in[2] (conv_mask_b) cancels exactly under softmax shift-invariance.
  const float* w1  = (const float*)d_in[3];
  const float* b1  = (const float*)d_in[4];
  const float* lnw = (const float*)d_in[5];
  const float* lnb = (const float*)d_in[6];
  const float* w2  = (const float*)d_in[7];
  const float* b2  = (const float*)d_in[8];
  float* out = (float*)d_out;

  char* ws = (char*)d_ws;
  float* part_pc  = (float*)ws;                                // B*NB*C = 1 MB
  float* part_m   = (float*)(ws + (size_t)B * NB * C * 4);
  float* part_z   = part_m + B * NB;
  float* add_term = part_z + B * NB;

  k_fused<<<dim3(NB, B), 512, 0, stream>>>(x, cw, part_pc, part_m, part_z);
  k_tail<<<dim3(B), C, 0, stream>>>(part_pc, part_m, part_z,
                                    w1, b1, lnw, lnb, w2, b2, add_term);
  k_add<<<dim3(B * C), 256, 0, stream>>>(x, add_term, out);
}